// Round 1
// baseline (398.517 us; speedup 1.0000x reference)
//
#include <hip/hip_runtime.h>

#define BATCH 4
#define NHEADS 3
#define SEQ 2048
#define HDIM 256
#define EMBD 768
#define MTOT (BATCH*SEQ)          // 8192
#define WSZ (NHEADS*EMBD*HDIM)    // 589824 per projection weight

typedef unsigned short u16x8 __attribute__((ext_vector_type(8)));
typedef unsigned short u16x4 __attribute__((ext_vector_type(4)));
typedef __bf16 bf16x8 __attribute__((ext_vector_type(8)));
typedef float fx4 __attribute__((ext_vector_type(4)));

__device__ __forceinline__ unsigned short f2bf(float x) {
    union { float f; unsigned int u; } v; v.f = x;
    unsigned int r = v.u + 0x7fffu + ((v.u >> 16) & 1u);
    return (unsigned short)(r >> 16);
}

__device__ __forceinline__ fx4 mfma16(u16x8 a, u16x8 b, fx4 c) {
    return __builtin_amdgcn_mfma_f32_16x16x32_bf16(
        __builtin_bit_cast(bf16x8, a), __builtin_bit_cast(bf16x8, b), c, 0, 0, 0);
}

// ---------------------------------------------------------------------------
// Kernel 1: cast + transpose weights.
// Wt[t][n=h*256+f][e] = W_t[h][e][f]  (bf16), t in {k,v,q}
// Wot[n][k] = Wo[k][n]                (bf16)
// ---------------------------------------------------------------------------
__global__ __launch_bounds__(256) void castw_kernel(
    const float* __restrict__ Wk, const float* __restrict__ Wv,
    const float* __restrict__ Wq, const float* __restrict__ Wo,
    unsigned short* __restrict__ Wt, unsigned short* __restrict__ Wot)
{
    int idx = blockIdx.x * 256 + threadIdx.x;
    if (idx < 3 * WSZ) {
        int t = idx / WSZ;
        int r = idx - t * WSZ;
        int n = r / EMBD;
        int e = r - n * EMBD;
        int h = n >> 8, f = n & 255;
        const float* Wsrc = (t == 0) ? Wk : (t == 1) ? Wv : Wq;
        Wt[idx] = f2bf(Wsrc[(h * EMBD + e) * HDIM + f]);
    } else if (idx < 4 * WSZ) {
        int r = idx - 3 * WSZ;
        int n = r / EMBD, k = r - n * EMBD;
        Wot[n * EMBD + k] = f2bf(Wo[k * EMBD + n]);
    }
}

// ---------------------------------------------------------------------------
// Kernel 2: projection GEMM. C[m][n] = sum_e A[m][e] * Wt[n][e]
// z=0: keys -> Kg [b][h][s][f];  z=1: values -> Vg [b][h][f][s] (transposed);
// z=2: queries -> Qg [b][h][s][f]. Block tile 128(M)x128(N), BK=32.
// ---------------------------------------------------------------------------
__global__ __launch_bounds__(256) void proj_kernel(
    const float* __restrict__ Ak, const float* __restrict__ Av,
    const float* __restrict__ Aq, const unsigned short* __restrict__ Wt,
    unsigned short* __restrict__ Kg, unsigned short* __restrict__ Vg,
    unsigned short* __restrict__ Qg)
{
    __shared__ alignas(16) unsigned short As[128 * 40];
    __shared__ alignas(16) unsigned short Bs[128 * 40];

    int z = blockIdx.z;
    const float* A = (z == 0) ? Ak : (z == 1) ? Av : Aq;
    const unsigned short* W = Wt + z * WSZ;
    int m0 = blockIdx.x * 128;
    int n0 = blockIdx.y * 128;
    int tid = threadIdx.x;
    int w = tid >> 6, ln = tid & 63;
    int lane16 = ln & 15, quad = ln >> 4;

    fx4 acc[2][8];
    for (int i = 0; i < 2; ++i)
        for (int j = 0; j < 8; ++j) acc[i][j] = (fx4){0.f, 0.f, 0.f, 0.f};

    int arow = tid >> 1, ac0 = (tid & 1) * 16;   // A stage: 128x32 fp32
    int brow = tid >> 1, bc0 = (tid & 1) * 16;   // B stage: 128x32 bf16

    for (int kb = 0; kb < EMBD; kb += 32) {
        __syncthreads();
        {   // stage A (fp32 -> bf16)
            const fx4* src = (const fx4*)(A + (m0 + arow) * EMBD + kb + ac0);
            fx4 v0 = src[0], v1 = src[1], v2 = src[2], v3 = src[3];
            u16x8 o0, o1;
            o0[0]=f2bf(v0[0]); o0[1]=f2bf(v0[1]); o0[2]=f2bf(v0[2]); o0[3]=f2bf(v0[3]);
            o0[4]=f2bf(v1[0]); o0[5]=f2bf(v1[1]); o0[6]=f2bf(v1[2]); o0[7]=f2bf(v1[3]);
            o1[0]=f2bf(v2[0]); o1[1]=f2bf(v2[1]); o1[2]=f2bf(v2[2]); o1[3]=f2bf(v2[3]);
            o1[4]=f2bf(v3[0]); o1[5]=f2bf(v3[1]); o1[6]=f2bf(v3[2]); o1[7]=f2bf(v3[3]);
            *(u16x8*)&As[arow * 40 + ac0] = o0;
            *(u16x8*)&As[arow * 40 + ac0 + 8] = o1;
        }
        {   // stage B (bf16 copy)
            const u16x8* src = (const u16x8*)(W + (n0 + brow) * EMBD + kb + bc0);
            *(u16x8*)&Bs[brow * 40 + bc0] = src[0];
            *(u16x8*)&Bs[brow * 40 + bc0 + 8] = src[1];
        }
        __syncthreads();
        u16x8 bfr[8];
        for (int ns = 0; ns < 8; ++ns)
            bfr[ns] = *(const u16x8*)&Bs[(ns * 16 + lane16) * 40 + quad * 8];
        for (int ms = 0; ms < 2; ++ms) {
            u16x8 af = *(const u16x8*)&As[(w * 32 + ms * 16 + lane16) * 40 + quad * 8];
            for (int ns = 0; ns < 8; ++ns)
                acc[ms][ns] = mfma16(af, bfr[ns], acc[ms][ns]);
        }
    }

    for (int ms = 0; ms < 2; ++ms) {
        int mbase = m0 + w * 32 + ms * 16 + quad * 4;
        int b = mbase >> 11;
        int s = mbase & 2047;
        for (int ns = 0; ns < 8; ++ns) {
            int n = n0 + ns * 16 + lane16;
            int h = n >> 8, f = n & 255;
            if (z == 1) {
                u16x4 pk;
                pk[0] = f2bf(acc[ms][ns][0]); pk[1] = f2bf(acc[ms][ns][1]);
                pk[2] = f2bf(acc[ms][ns][2]); pk[3] = f2bf(acc[ms][ns][3]);
                *(u16x4*)&Vg[((b * NHEADS + h) * HDIM + f) * SEQ + s] = pk;
            } else {
                unsigned short* dst = (z == 0) ? Kg : Qg;
                for (int r = 0; r < 4; ++r)
                    dst[((b * NHEADS + h) * SEQ + s + r) * HDIM + f] = f2bf(acc[ms][ns][r]);
            }
        }
    }
}

// ---------------------------------------------------------------------------
// Kernel 3: causal flash attention.
// Block: one (b,h) x 64 q-rows; 4 waves x 16 q-rows; k-tiles of 32.
// ---------------------------------------------------------------------------
__global__ __launch_bounds__(256) void attn_kernel(
    const unsigned short* __restrict__ Kg, const unsigned short* __restrict__ Vg,
    const unsigned short* __restrict__ Qg, unsigned short* __restrict__ heads)
{
    __shared__ alignas(16) unsigned short Ks[32 * 264];   // [k=32][f=256] pad->264
    __shared__ alignas(16) unsigned short Vs[256 * 40];   // [f=256][k=32] pad->40
    __shared__ alignas(16) unsigned short Ps[4 * 16 * 40];// per-wave P [16][32] pad->40

    int bx = blockIdx.x;
    int qt = 31 - (bx / 12);          // heavy (long) q-tiles dispatch first
    int bh = bx % 12;                 // b*3 + h
    int tid = threadIdx.x;
    int w = tid >> 6, ln = tid & 63;
    int lane16 = ln & 15, quad = ln >> 4;

    const unsigned short* Kbase = Kg + bh * (SEQ * HDIM);
    const unsigned short* Vbase = Vg + bh * (SEQ * HDIM);  // [HD][S]
    const unsigned short* Qbase = Qg + bh * (SEQ * HDIM);

    int q0 = qt * 64 + w * 16;

    u16x8 qf[8];
    {
        const unsigned short* qrow = Qbase + (q0 + lane16) * HDIM + quad * 8;
        for (int c = 0; c < 8; ++c) qf[c] = *(const u16x8*)(qrow + c * 32);
    }

    fx4 o[16];
    for (int i = 0; i < 16; ++i) o[i] = (fx4){0.f, 0.f, 0.f, 0.f};
    float mrow[4] = {-1e30f, -1e30f, -1e30f, -1e30f};
    float lrow[4] = {0.f, 0.f, 0.f, 0.f};

    const float Cs = 1.4426950408889634f / 45.254833995939045f; // log2e/sqrt(2048)
    const float NEGINF = -__builtin_inff();

    int ktmax = 2 * qt + 1;
    int ksrow = tid >> 3, kseg = tid & 7;
    for (int kt = 0; kt <= ktmax; ++kt) {
        __syncthreads();
        {   // stage K tile [32][256]
            const u16x8* src = (const u16x8*)(Kbase + (kt * 32 + ksrow) * HDIM + kseg * 32);
            u16x8* dst = (u16x8*)&Ks[ksrow * 264 + kseg * 32];
            dst[0] = src[0]; dst[1] = src[1]; dst[2] = src[2]; dst[3] = src[3];
        }
        {   // stage V^T tile [256][32]
            const u16x8* src = (const u16x8*)(Vbase + tid * SEQ + kt * 32);
            u16x8* dst = (u16x8*)&Vs[tid * 40];
            dst[0] = src[0]; dst[1] = src[1]; dst[2] = src[2]; dst[3] = src[3];
        }
        __syncthreads();

        // QK^T: two 16x16 score tiles over 32 keys
        fx4 sacc[2];
        for (int kh = 0; kh < 2; ++kh) {
            fx4 sa = (fx4){0.f, 0.f, 0.f, 0.f};
            for (int c = 0; c < 8; ++c) {
                u16x8 kf = *(const u16x8*)&Ks[(kh * 16 + lane16) * 264 + c * 32 + quad * 8];
                sa = mfma16(qf[c], kf, sa);
            }
            sacc[kh] = sa;
        }

        // online softmax (rows quad*4+r, col lane16 / lane16+16)
        int qrow_base = qt * 64 + w * 16 + quad * 4;
        int kcol0 = kt * 32 + lane16;
        for (int r = 0; r < 4; ++r) {
            int qg = qrow_base + r;
            float t0 = (kcol0      <= qg) ? sacc[0][r] * Cs : NEGINF;
            float t1 = (kcol0 + 16 <= qg) ? sacc[1][r] * Cs : NEGINF;
            float rm = fmaxf(t0, t1);
            for (int off = 1; off < 16; off <<= 1) rm = fmaxf(rm, __shfl_xor(rm, off, 16));
            float mnew = fmaxf(mrow[r], rm);
            float alpha = exp2f(mrow[r] - mnew);
            float p0 = exp2f(t0 - mnew);
            float p1 = exp2f(t1 - mnew);
            float rs = p0 + p1;
            for (int off = 1; off < 16; off <<= 1) rs += __shfl_xor(rs, off, 16);
            lrow[r] = lrow[r] * alpha + rs;
            mrow[r] = mnew;
            for (int ft = 0; ft < 16; ++ft) o[ft][r] *= alpha;
            Ps[(w * 16 + quad * 4 + r) * 40 + lane16] = f2bf(p0);
            Ps[(w * 16 + quad * 4 + r) * 40 + 16 + lane16] = f2bf(p1);
        }
        __syncthreads();   // P C-layout -> A-layout via LDS (uniform across waves)

        // PV: O[16q][256f] += P[16][32] * V[32][256]
        u16x8 pf = *(const u16x8*)&Ps[(w * 16 + lane16) * 40 + quad * 8];
        for (int ft = 0; ft < 16; ++ft) {
            u16x8 vf = *(const u16x8*)&Vs[(ft * 16 + lane16) * 40 + quad * 8];
            o[ft] = mfma16(pf, vf, o[ft]);
        }
    }

    // epilogue: normalize, store heads [m=b*S+q][h*256+f] bf16
    float inv[4];
    for (int r = 0; r < 4; ++r) inv[r] = 1.f / lrow[r];
    int b = bh / 3, h = bh % 3;
    int qrow_base = qt * 64 + w * 16 + quad * 4;
    for (int ft = 0; ft < 16; ++ft) {
        int col = h * HDIM + ft * 16 + lane16;
        for (int r = 0; r < 4; ++r) {
            int m = b * SEQ + qrow_base + r;
            heads[m * EMBD + col] = f2bf(o[ft][r] * inv[r]);
        }
    }
}

// ---------------------------------------------------------------------------
// Kernel 4: output projection. out[m][n] = sum_k heads[m][k]*Wot[n][k] + bo[n]
// ---------------------------------------------------------------------------
__global__ __launch_bounds__(256) void outproj_kernel(
    const unsigned short* __restrict__ A, const unsigned short* __restrict__ Wot,
    const float* __restrict__ bo, float* __restrict__ out)
{
    __shared__ alignas(16) unsigned short As[128 * 40];
    __shared__ alignas(16) unsigned short Bs[128 * 40];

    int m0 = blockIdx.x * 128, n0 = blockIdx.y * 128;
    int tid = threadIdx.x;
    int w = tid >> 6, ln = tid & 63;
    int lane16 = ln & 15, quad = ln >> 4;

    fx4 acc[2][8];
    for (int i = 0; i < 2; ++i)
        for (int j = 0; j < 8; ++j) acc[i][j] = (fx4){0.f, 0.f, 0.f, 0.f};

    int row = tid >> 1, c0 = (tid & 1) * 16;
    for (int kb = 0; kb < EMBD; kb += 32) {
        __syncthreads();
        {
            const u16x8* src = (const u16x8*)(A + (m0 + row) * EMBD + kb + c0);
            *(u16x8*)&As[row * 40 + c0]     = src[0];
            *(u16x8*)&As[row * 40 + c0 + 8] = src[1];
        }
        {
            const u16x8* src = (const u16x8*)(Wot + (n0 + row) * EMBD + kb + c0);
            *(u16x8*)&Bs[row * 40 + c0]     = src[0];
            *(u16x8*)&Bs[row * 40 + c0 + 8] = src[1];
        }
        __syncthreads();
        u16x8 bfr[8];
        for (int ns = 0; ns < 8; ++ns)
            bfr[ns] = *(const u16x8*)&Bs[(ns * 16 + lane16) * 40 + quad * 8];
        for (int ms = 0; ms < 2; ++ms) {
            u16x8 af = *(const u16x8*)&As[(w * 32 + ms * 16 + lane16) * 40 + quad * 8];
            for (int ns = 0; ns < 8; ++ns)
                acc[ms][ns] = mfma16(af, bfr[ns], acc[ms][ns]);
        }
    }

    for (int ms = 0; ms < 2; ++ms) {
        int mb = m0 + w * 32 + ms * 16 + quad * 4;
        for (int ns = 0; ns < 8; ++ns) {
            int n = n0 + ns * 16 + lane16;
            float bias = bo[n];
            for (int r = 0; r < 4; ++r)
                out[(mb + r) * EMBD + n] = acc[ms][ns][r] + bias;
        }
    }
}

// ---------------------------------------------------------------------------
extern "C" void kernel_launch(void* const* d_in, const int* in_sizes, int n_in,
                              void* d_out, int out_size, void* d_ws, size_t ws_size,
                              hipStream_t stream) {
    const float* Ak = (const float*)d_in[0];
    const float* Av = (const float*)d_in[1];
    const float* Aq = (const float*)d_in[2];
    const float* Wk = (const float*)d_in[3];
    const float* Wv = (const float*)d_in[4];
    const float* Wq = (const float*)d_in[5];
    const float* Wo = (const float*)d_in[6];
    const float* bo = (const float*)d_in[7];
    float* out = (float*)d_out;

    unsigned short* ws = (unsigned short*)d_ws;
    unsigned short* Wt    = ws;                 // 3*589824
    unsigned short* Wot   = ws + 1769472;       // 589824
    unsigned short* Kg    = ws + 2359296;       // 6291456
    unsigned short* Vg    = ws + 8650752;       // 6291456
    unsigned short* Qg    = ws + 14942208;      // 6291456
    unsigned short* heads = ws + 21233664;      // 6291456  (total ~55 MB)

    castw_kernel<<<dim3(9216), dim3(256), 0, stream>>>(Wk, Wv, Wq, Wo, Wt, Wot);
    proj_kernel<<<dim3(64, 6, 3), dim3(256), 0, stream>>>(Ak, Av, Aq, Wt, Kg, Vg, Qg);
    attn_kernel<<<dim3(384), dim3(256), 0, stream>>>(Kg, Vg, Qg, heads);
    outproj_kernel<<<dim3(64, 6), dim3(256), 0, stream>>>(heads, Wot, bo, out);
}